// Round 2
// baseline (413.162 us; speedup 1.0000x reference)
//
#include <hip/hip_runtime.h>

#define B_  2
#define S_  2048
#define D_  1024
#define H_  16
#define HD_ 64
#define M_  (B_ * S_)  // 4096

typedef short bf16x8 __attribute__((ext_vector_type(8)));
typedef float f32x4  __attribute__((ext_vector_type(4)));

#define MFMA(c, a, b) (c) = __builtin_amdgcn_mfma_f32_16x16x32_bf16((a), (b), (c), 0, 0, 0)

__device__ __forceinline__ unsigned short f2bf(float f) {
    union { float f; unsigned int u; } v; v.f = f;
    unsigned int u = v.u;
    u += 0x7FFFu + ((u >> 16) & 1u);   // RNE
    return (unsigned short)(u >> 16);
}

// ---------------------------------------------------------------------------
// GEMM: C[M,N] = A[M,1024] @ W[1024,N] + bias.  64x64 tile, 4 waves, BK=32.
// HEADSPLIT: store bf16 to [B][H][S][HD]; else store f32 row-major [M][D].
// ---------------------------------------------------------------------------
template <bool HEADSPLIT, bool A_IS_BF16>
__global__ __launch_bounds__(256) void gemm_kernel(
    const void* __restrict__ Aptr, const float* __restrict__ W,
    const float* __restrict__ bias, void* __restrict__ Cptr)
{
    __shared__ unsigned short As[64][40];  // [m][k], row stride 80B (16B-aligned)
    __shared__ unsigned short Bs[64][40];  // [n][k] (W transposed)

    const int tid  = threadIdx.x;
    const int lane = tid & 63;
    const int wid  = tid >> 6;
    const int m0   = blockIdx.y * 64;
    const int n0   = blockIdx.x * 64;
    const int wm   = (wid >> 1) * 32;
    const int wn   = (wid & 1) * 32;
    const int lr   = lane & 15;
    const int lg   = lane >> 4;

    f32x4 acc[2][2] = {};

    for (int k0 = 0; k0 < 1024; k0 += 32) {
        __syncthreads();
        {   // stage A tile 64x32 (8 elems/thread)
            const int r = tid >> 2, cg = tid & 3;
            if constexpr (A_IS_BF16) {
                const unsigned short* a =
                    (const unsigned short*)Aptr + (size_t)(m0 + r) * D_ + k0 + cg * 8;
                *(bf16x8*)&As[r][cg * 8] = *(const bf16x8*)a;
            } else {
                const float* a = (const float*)Aptr + (size_t)(m0 + r) * D_ + k0 + cg * 8;
#pragma unroll
                for (int j = 0; j < 8; ++j) As[r][cg * 8 + j] = f2bf(a[j]);
            }
        }
        {   // stage W tile 32x64 transposed into Bs[n][k]
            const int kk = tid >> 3, cg = tid & 7;
            const float* wp = W + (size_t)(k0 + kk) * D_ + n0 + cg * 8;
#pragma unroll
            for (int j = 0; j < 8; ++j) Bs[cg * 8 + j][kk] = f2bf(wp[j]);
        }
        __syncthreads();

        bf16x8 af[2], bfr[2];
#pragma unroll
        for (int i = 0; i < 2; ++i)
            af[i] = *(const bf16x8*)&As[wm + i * 16 + lr][lg * 8];
#pragma unroll
        for (int j = 0; j < 2; ++j)
            bfr[j] = *(const bf16x8*)&Bs[wn + j * 16 + lr][lg * 8];
#pragma unroll
        for (int i = 0; i < 2; ++i)
#pragma unroll
            for (int j = 0; j < 2; ++j)
                MFMA(acc[i][j], af[i], bfr[j]);
    }

#pragma unroll
    for (int i = 0; i < 2; ++i) {
#pragma unroll
        for (int j = 0; j < 2; ++j) {
            const int n = n0 + wn + j * 16 + lr;
            const float bv = bias[n];
#pragma unroll
            for (int r4 = 0; r4 < 4; ++r4) {
                const int m = m0 + wm + i * 16 + lg * 4 + r4;
                const float val = acc[i][j][r4] + bv;
                if constexpr (HEADSPLIT) {
                    const int b = m >> 11, s = m & (S_ - 1);
                    const int h = n >> 6, hd = n & 63;
                    ((unsigned short*)Cptr)[(((size_t)(b * H_ + h) * S_) + s) * HD_ + hd] =
                        f2bf(val);
                } else {
                    ((float*)Cptr)[(size_t)m * D_ + n] = val;
                }
            }
        }
    }
}

// ---------------------------------------------------------------------------
// Flash attention, causal.  Block = (qblock of 64 rows, one b*h).  4 waves,
// 16 Q rows/wave.  KV tiles of 32, staged in LDS.  Online softmax in the
// C/D fragment layout: col = lane&15, row = (lane>>4)*4 + reg.
// ---------------------------------------------------------------------------
__global__ __launch_bounds__(256) void attn_kernel(
    const unsigned short* __restrict__ Q, const unsigned short* __restrict__ K,
    const unsigned short* __restrict__ V, unsigned short* __restrict__ CTX)
{
    __shared__ unsigned short Ks[32][72];      // [kv][d], stride 144B
    __shared__ unsigned short Vt[64][40];      // [d][kv], stride 80B
    __shared__ unsigned short Ps[4][16][40];   // per-wave P buffer [q][kv]

    const int tid  = threadIdx.x;
    const int lane = tid & 63;
    const int w    = tid >> 6;
    const int lr   = lane & 15;
    const int lg   = lane >> 4;
    const int q0   = blockIdx.x * 64;
    const int bh   = blockIdx.y;            // b*H + h
    const size_t base = (size_t)bh * S_ * HD_;

    // Q fragments (A operand), rows q0 + w*16 + lr, held in registers
    const int qrow = q0 + w * 16 + lr;
    bf16x8 qf[2];
#pragma unroll
    for (int ks = 0; ks < 2; ++ks)
        qf[ks] = *(const bf16x8*)&Q[base + (size_t)qrow * HD_ + ks * 32 + lg * 8];

    f32x4 acc[4] = {};
    f32x4 mrun, lrun;
#pragma unroll
    for (int i = 0; i < 4; ++i) { mrun[i] = -1e30f; lrun[i] = 0.0f; }

    const int qg_hi = q0 + w * 16 + 15;     // highest q row this wave owns
    const int nkv   = (q0 >> 5) + 2;        // kv blocks through the diagonal

    for (int kv = 0; kv < nkv; ++kv) {
        const int kv0 = kv * 32;
        __syncthreads();
        {   // cooperative staging: K rows kv0..kv0+31, V transposed
            const int r = tid >> 3, cg = tid & 7;
            const unsigned short* kp = &K[base + (size_t)(kv0 + r) * HD_ + cg * 8];
            *(bf16x8*)&Ks[r][cg * 8] = *(const bf16x8*)kp;
            const unsigned short* vp = &V[base + (size_t)(kv0 + r) * HD_ + cg * 8];
#pragma unroll
            for (int j = 0; j < 8; ++j) Vt[cg * 8 + j][r] = vp[j];
        }
        __syncthreads();

        if (kv0 <= qg_hi) {
            // ---- QK^T: logits 16 x 32 for this wave ----
            f32x4 c[2] = {};
#pragma unroll
            for (int kt = 0; kt < 2; ++kt)
#pragma unroll
                for (int ks = 0; ks < 2; ++ks) {
                    bf16x8 kf = *(const bf16x8*)&Ks[kt * 16 + lr][ks * 32 + lg * 8];
                    MFMA(c[kt], qf[ks], kf);
                }

            // ---- scale + causal mask ----
            float lv[2][4];
#pragma unroll
            for (int kt = 0; kt < 2; ++kt) {
                const int kg = kv0 + kt * 16 + lr;
#pragma unroll
                for (int r4 = 0; r4 < 4; ++r4) {
                    const int qg = q0 + w * 16 + lg * 4 + r4;
                    lv[kt][r4] = (kg > qg) ? -1e9f : c[kt][r4] * 0.125f;
                }
            }
            // ---- row max (reduce over 16 lanes = 16 cols, 2 tiles) ----
            f32x4 tmax;
#pragma unroll
            for (int r4 = 0; r4 < 4; ++r4) tmax[r4] = fmaxf(lv[0][r4], lv[1][r4]);
#pragma unroll
            for (int off = 1; off < 16; off <<= 1)
#pragma unroll
                for (int r4 = 0; r4 < 4; ++r4)
                    tmax[r4] = fmaxf(tmax[r4], __shfl_xor(tmax[r4], off));

            f32x4 mnew, alpha;
#pragma unroll
            for (int r4 = 0; r4 < 4; ++r4) {
                mnew[r4]  = fmaxf(mrun[r4], tmax[r4]);
                alpha[r4] = __expf(mrun[r4] - mnew[r4]);
            }
            float p[2][4];
            f32x4 tsum;
#pragma unroll
            for (int r4 = 0; r4 < 4; ++r4) {
                p[0][r4] = __expf(lv[0][r4] - mnew[r4]);
                p[1][r4] = __expf(lv[1][r4] - mnew[r4]);
                tsum[r4] = p[0][r4] + p[1][r4];
            }
#pragma unroll
            for (int off = 1; off < 16; off <<= 1)
#pragma unroll
                for (int r4 = 0; r4 < 4; ++r4)
                    tsum[r4] += __shfl_xor(tsum[r4], off);
#pragma unroll
            for (int r4 = 0; r4 < 4; ++r4) {
                lrun[r4] = lrun[r4] * alpha[r4] + tsum[r4];
                mrun[r4] = mnew[r4];
            }
            // rescale O accumulator
#pragma unroll
            for (int n = 0; n < 4; ++n)
#pragma unroll
                for (int r4 = 0; r4 < 4; ++r4) acc[n][r4] *= alpha[r4];

            // ---- P -> LDS (relayout to A-fragment) ----
#pragma unroll
            for (int kt = 0; kt < 2; ++kt)
#pragma unroll
                for (int r4 = 0; r4 < 4; ++r4)
                    Ps[w][lg * 4 + r4][kt * 16 + lr] = f2bf(p[kt][r4]);
            // per-wave RAW through LDS: DS ops are in-order per wave; fence the
            // compiler and drain lgkm before the re-read.
            asm volatile("s_waitcnt lgkmcnt(0)" ::: "memory");

            bf16x8 pf = *(const bf16x8*)&Ps[w][lr][lg * 8];

            // ---- PV: acc[n] += P(16x32) @ V(32x16[n]) ----
#pragma unroll
            for (int n = 0; n < 4; ++n) {
                bf16x8 vb = *(const bf16x8*)&Vt[n * 16 + lr][lg * 8];
                MFMA(acc[n], pf, vb);
            }
        }
    }

    const int b = bh >> 4, h = bh & 15;
#pragma unroll
    for (int r4 = 0; r4 < 4; ++r4) {
        const int row = q0 + w * 16 + lg * 4 + r4;
        const float linv = 1.0f / lrun[r4];
#pragma unroll
        for (int n = 0; n < 4; ++n) {
            const int d = n * 16 + lr;
            CTX[((size_t)b * S_ + row) * D_ + h * HD_ + d] = f2bf(acc[n][r4] * linv);
        }
    }
}

// ---------------------------------------------------------------------------
extern "C" void kernel_launch(void* const* d_in, const int* in_sizes, int n_in,
                              void* d_out, int out_size, void* d_ws, size_t ws_size,
                              hipStream_t stream)
{
    const float* x  = (const float*)d_in[0];
    const float* wq = (const float*)d_in[1];
    const float* bq = (const float*)d_in[2];
    const float* wk = (const float*)d_in[3];
    const float* bk = (const float*)d_in[4];
    const float* wv = (const float*)d_in[5];
    const float* bv = (const float*)d_in[6];
    const float* wo = (const float*)d_in[7];
    const float* bo = (const float*)d_in[8];
    float* out = (float*)d_out;

    const size_t NELEM = (size_t)B_ * H_ * S_ * HD_;  // 4,194,304
    unsigned short* qb  = (unsigned short*)d_ws;
    unsigned short* kb  = qb + NELEM;
    unsigned short* vb  = kb + NELEM;
    unsigned short* ctx = vb + NELEM;

    dim3 blk(256);
    dim3 gproj(D_ / 64, M_ / 64);       // (16, 64)
    gemm_kernel<true, false><<<gproj, blk, 0, stream>>>(x, wq, bq, qb);
    gemm_kernel<true, false><<<gproj, blk, 0, stream>>>(x, wk, bk, kb);
    gemm_kernel<true, false><<<gproj, blk, 0, stream>>>(x, wv, bv, vb);

    dim3 gattn(S_ / 64, B_ * H_);       // (32, 32)
    attn_kernel<<<gattn, blk, 0, stream>>>(qb, kb, vb, ctx);

    gemm_kernel<false, true><<<gproj, blk, 0, stream>>>(ctx, wo, bo, out);
}

// Round 3
// 256.256 us; speedup vs baseline: 1.6123x; 1.6123x over previous
//
#include <hip/hip_runtime.h>

#define S_  2048
#define D_  1024
#define H_  16
#define HD_ 64
#define M_  4096
#define K_  1024
#define NEL 4194304   // B*H*S*HD = 4M elements

typedef short  bf16x8 __attribute__((ext_vector_type(8)));
typedef float  f32x4  __attribute__((ext_vector_type(4)));
typedef unsigned short u16;
typedef unsigned short u16x4 __attribute__((ext_vector_type(4)));

#define MFMA(c,a,b) (c) = __builtin_amdgcn_mfma_f32_16x16x32_bf16((a),(b),(c),0,0,0)

// Q pre-scale: 1/sqrt(64) * log2(e)  -> softmax works in exp2 domain
#define QSCALE 0.18033688011112042f

__device__ __forceinline__ u16 f2bf(float f) {
    union { float f; unsigned u; } v; v.f = f;
    unsigned u = v.u;
    u += 0x7FFFu + ((u >> 16) & 1u);   // RNE
    return (u16)(u >> 16);
}

__device__ __forceinline__ void gload16(const void* g, void* l) {
    __builtin_amdgcn_global_load_lds(
        (const __attribute__((address_space(1))) unsigned*)g,
        (__attribute__((address_space(3))) unsigned*)l, 16, 0, 0);
}

// ---------------------------------------------------------------------------
// x f32 -> bf16 (4M elems, 8/thread)
// ---------------------------------------------------------------------------
__global__ __launch_bounds__(256) void cvt_x(const float* __restrict__ x,
                                             u16* __restrict__ xb) {
    const int i = (blockIdx.x * 256 + threadIdx.x) * 8;
    f32x4 a = *(const f32x4*)&x[i];
    f32x4 b = *(const f32x4*)&x[i + 4];
    u16 t[8];
#pragma unroll
    for (int j = 0; j < 4; ++j) { t[j] = f2bf(a[j]); t[4 + j] = f2bf(b[j]); }
    *(bf16x8*)&xb[i] = *(const bf16x8*)t;
}

// ---------------------------------------------------------------------------
// W[k][n] f32 -> Wt[n][k] bf16, 64x64 LDS-tiled transpose.  z selects weight.
// ---------------------------------------------------------------------------
__global__ __launch_bounds__(256) void cvt_w(const float* __restrict__ w0,
                                             const float* __restrict__ w1,
                                             const float* __restrict__ w2,
                                             const float* __restrict__ w3,
                                             u16* __restrict__ Wt) {
    __shared__ float T[64][65];
    const float* W = blockIdx.z == 0 ? w0 : blockIdx.z == 1 ? w1
                   : blockIdx.z == 2 ? w2 : w3;
    const int k0 = blockIdx.x * 64, n0 = blockIdx.y * 64;
    const int r  = threadIdx.x >> 2, c0 = (threadIdx.x & 3) * 16;
#pragma unroll
    for (int j = 0; j < 4; ++j)
        *(f32x4*)&T[r][c0 + j * 4] = *(const f32x4*)&W[(size_t)(k0 + r) * D_ + n0 + c0 + j * 4];
    __syncthreads();
    u16 tmp[16];
#pragma unroll
    for (int j = 0; j < 16; ++j) tmp[j] = f2bf(T[c0 + j][r]);
    u16* dst = Wt + ((size_t)blockIdx.z * 1024 + n0 + r) * K_ + k0 + c0;
    *(bf16x8*)dst       = *(const bf16x8*)tmp;
    *(bf16x8*)(dst + 8) = *(const bf16x8*)(tmp + 8);
}

// ---------------------------------------------------------------------------
// m97-style GEMM: C[M,N] = A[M,1024](bf16) @ Wt[N,1024]^T + bias.
// BK=32, BN=128, 4 waves, global_load_lds(16B) staging, 2-barrier loop.
// MODE 0: QKV fused epilogue (headsplit bf16; Q scaled; V transposed).
// MODE 1: f32 row-major out.
// ---------------------------------------------------------------------------
template <int BM, int MODE>
__global__ __launch_bounds__(256) void gemm2(
    const u16* __restrict__ A, const u16* __restrict__ Bt,
    const float* __restrict__ bias, void* __restrict__ Out)
{
    __shared__ u16 As[BM * 32];
    __shared__ u16 Bs[128 * 32];
    const int tid = threadIdx.x, lane = tid & 63, wid = tid >> 6;
    const int lr = lane & 15, lg = lane >> 4;
    const int n0 = blockIdx.x * 128, m0 = blockIdx.y * BM;
    const int wm = (wid >> 1) * (BM / 2), wn = (wid & 1) * 64;
    const int lrow = lane >> 2, lch = lane & 3;   // staging: 4 lanes/row, 16B chunks

    f32x4 acc[BM / 32][4] = {};

    for (int k0 = 0; k0 < K_; k0 += 32) {
        __syncthreads();
#pragma unroll
        for (int t = 0; t < BM / 64; ++t) {      // A tile BMx32
            const int row = wid * (BM / 4) + t * 16 + lrow;
            gload16(A + (size_t)(m0 + row) * K_ + k0 + lch * 8,
                    (u16*)As + row * 32 + lch * 8);
        }
#pragma unroll
        for (int t = 0; t < 2; ++t) {            // B tile 128x32
            const int row = wid * 32 + t * 16 + lrow;
            gload16(Bt + (size_t)(n0 + row) * K_ + k0 + lch * 8,
                    (u16*)Bs + row * 32 + lch * 8);
        }
        __syncthreads();

        bf16x8 af[BM / 32], bf[4];
#pragma unroll
        for (int i = 0; i < BM / 32; ++i)
            af[i] = *(const bf16x8*)&As[(wm + i * 16 + lr) * 32 + lg * 8];
#pragma unroll
        for (int j = 0; j < 4; ++j)
            bf[j] = *(const bf16x8*)&Bs[(wn + j * 16 + lr) * 32 + lg * 8];
#pragma unroll
        for (int i = 0; i < BM / 32; ++i)
#pragma unroll
            for (int j = 0; j < 4; ++j) MFMA(acc[i][j], af[i], bf[j]);
    }

#pragma unroll
    for (int i = 0; i < BM / 32; ++i) {
#pragma unroll
        for (int j = 0; j < 4; ++j) {
            const int n = n0 + wn + j * 16 + lr;
            const float bv = bias[n];
            const int m = m0 + wm + i * 16 + lg * 4;     // +r4
            if constexpr (MODE == 0) {
                u16* qkv = (u16*)Out;                     // q | k | vT regions
                const int which = n >> 10, nn = n & 1023;
                const int h = nn >> 6, hd = nn & 63;
                const int b = m >> 11, s = m & 2047;
                if (which == 2) {                         // V: [bh][hd][s]
                    u16x4 pk;
#pragma unroll
                    for (int r4 = 0; r4 < 4; ++r4) pk[r4] = f2bf(acc[i][j][r4] + bv);
                    *(u16x4*)&qkv[(size_t)2 * NEL +
                                  ((size_t)(b * H_ + h) * HD_ + hd) * S_ + s] = pk;
                } else {                                  // Q/K: [bh][s][hd]
                    const float sc = (which == 0) ? QSCALE : 1.0f;
                    const size_t bas = (size_t)which * NEL + (size_t)(b * H_ + h) * S_ * HD_;
#pragma unroll
                    for (int r4 = 0; r4 < 4; ++r4)
                        qkv[bas + (size_t)(s + r4) * HD_ + hd] =
                            f2bf((acc[i][j][r4] + bv) * sc);
                }
            } else {
                float* o = (float*)Out;
#pragma unroll
                for (int r4 = 0; r4 < 4; ++r4)
                    o[(size_t)(m + r4) * D_ + n] = acc[i][j][r4] + bv;
            }
        }
    }
}

// ---------------------------------------------------------------------------
// Flash attention, causal, exp2-domain (Q pre-scaled).  1 wave / block,
// 32 Q rows / wave, KV tiles of 64.  NO barriers, NO K/V LDS staging:
// K [bh][s][hd] and Vt [bh][hd][s] are fragment-ready for direct global
// b128 loads (L1/L2-resident).  P relayout via per-block LDS.
// ---------------------------------------------------------------------------
__global__ __launch_bounds__(64) void attn3(
    const u16* __restrict__ Q, const u16* __restrict__ K,
    const u16* __restrict__ Vt, u16* __restrict__ CTX)
{
    __shared__ u16 Ps[32][72];

    const int lane = threadIdx.x & 63;
    const int lr = lane & 15, lg = lane >> 4;
    const int qb32 = (gridDim.x - 1) - blockIdx.x;   // heavy blocks first
    const int bh = blockIdx.y;
    const int wq0 = qb32 * 32;
    const size_t base  = (size_t)bh * S_ * HD_;      // Q,K row-major
    const size_t vbase = (size_t)bh * HD_ * S_;      // Vt

    bf16x8 qf[2][2];
#pragma unroll
    for (int qi = 0; qi < 2; ++qi)
#pragma unroll
        for (int ks = 0; ks < 2; ++ks)
            qf[qi][ks] = *(const bf16x8*)&Q[base + (size_t)(wq0 + qi * 16 + lr) * HD_ +
                                            ks * 32 + lg * 8];

    f32x4 acc[2][4] = {};
    float m_[2][4], l_[2][4];
#pragma unroll
    for (int qi = 0; qi < 2; ++qi)
#pragma unroll
        for (int r4 = 0; r4 < 4; ++r4) { m_[qi][r4] = -1e30f; l_[qi][r4] = 0.0f; }

    const int nt = (wq0 >> 6) + 1;                   // kv tiles through diagonal

    for (int t = 0; t < nt; ++t) {
        const int kv0 = t * 64;

        // ---- QK^T: 32q x 64kv (exp2-domain logits; Q pre-scaled) ----
        f32x4 c[2][4] = {};
#pragma unroll
        for (int kt = 0; kt < 4; ++kt)
#pragma unroll
            for (int ks = 0; ks < 2; ++ks) {
                bf16x8 kf = *(const bf16x8*)&K[base + (size_t)(kv0 + kt * 16 + lr) * HD_ +
                                               ks * 32 + lg * 8];
#pragma unroll
                for (int qi = 0; qi < 2; ++qi) MFMA(c[qi][kt], qf[qi][ks], kf);
            }

        // ---- causal mask (only the ~1 diagonal tile per wave needs it) ----
        if (kv0 + 63 > wq0) {
#pragma unroll
            for (int qi = 0; qi < 2; ++qi)
#pragma unroll
                for (int kt = 0; kt < 4; ++kt) {
                    const int kg = kv0 + kt * 16 + lr;
#pragma unroll
                    for (int r4 = 0; r4 < 4; ++r4) {
                        const int qg = wq0 + qi * 16 + lg * 4 + r4;
                        if (kg > qg) c[qi][kt][r4] = -1e9f;
                    }
                }
        }

        // ---- row max over 64 kv: 3 local fmax + 4 shfl steps ----
        float rmax[2][4];
#pragma unroll
        for (int qi = 0; qi < 2; ++qi)
#pragma unroll
            for (int r4 = 0; r4 < 4; ++r4)
                rmax[qi][r4] = fmaxf(fmaxf(c[qi][0][r4], c[qi][1][r4]),
                                     fmaxf(c[qi][2][r4], c[qi][3][r4]));
#pragma unroll
        for (int off = 1; off < 16; off <<= 1)
#pragma unroll
            for (int qi = 0; qi < 2; ++qi)
#pragma unroll
                for (int r4 = 0; r4 < 4; ++r4)
                    rmax[qi][r4] = fmaxf(rmax[qi][r4], __shfl_xor(rmax[qi][r4], off));

        // ---- defer-max (T13): skip rescale if growth <= 11.5 (=e^8 in log2) ----
        int ok = 1;
#pragma unroll
        for (int qi = 0; qi < 2; ++qi)
#pragma unroll
            for (int r4 = 0; r4 < 4; ++r4)
                ok &= (rmax[qi][r4] <= m_[qi][r4] + 11.5f);
        if (!__all(ok)) {
#pragma unroll
            for (int qi = 0; qi < 2; ++qi)
#pragma unroll
                for (int r4 = 0; r4 < 4; ++r4) {
                    const float mn = fmaxf(m_[qi][r4], rmax[qi][r4]);
                    const float al = exp2f(m_[qi][r4] - mn);
                    m_[qi][r4] = mn;
                    l_[qi][r4] *= al;
#pragma unroll
                    for (int n = 0; n < 4; ++n) acc[qi][n][r4] *= al;
                }
        }

        // ---- P = exp2(logits - m), row sum, LDS relayout ----
        float tsum[2][4];
#pragma unroll
        for (int qi = 0; qi < 2; ++qi)
#pragma unroll
            for (int r4 = 0; r4 < 4; ++r4) {
#pragma unroll
                for (int kt = 0; kt < 4; ++kt) {
                    const float p = exp2f(c[qi][kt][r4] - m_[qi][r4]);
                    c[qi][kt][r4] = p;
                    Ps[qi * 16 + lg * 4 + r4][kt * 16 + lr] = f2bf(p);
                }
                tsum[qi][r4] = (c[qi][0][r4] + c[qi][1][r4]) +
                               (c[qi][2][r4] + c[qi][3][r4]);
            }
#pragma unroll
        for (int off = 1; off < 16; off <<= 1)
#pragma unroll
            for (int qi = 0; qi < 2; ++qi)
#pragma unroll
                for (int r4 = 0; r4 < 4; ++r4)
                    tsum[qi][r4] += __shfl_xor(tsum[qi][r4], off);
#pragma unroll
        for (int qi = 0; qi < 2; ++qi)
#pragma unroll
            for (int r4 = 0; r4 < 4; ++r4) l_[qi][r4] += tsum[qi][r4];

        asm volatile("s_waitcnt lgkmcnt(0)" ::: "memory");
        bf16x8 pf[2][2];
#pragma unroll
        for (int qi = 0; qi < 2; ++qi)
#pragma unroll
            for (int ksl = 0; ksl < 2; ++ksl)
                pf[qi][ksl] = *(const bf16x8*)&Ps[qi * 16 + lr][ksl * 32 + lg * 8];

        // ---- PV: acc[qi][n] += P(16x32) @ V(32x16), V read from Vt global ----
#pragma unroll
        for (int n = 0; n < 4; ++n)
#pragma unroll
            for (int ksl = 0; ksl < 2; ++ksl) {
                bf16x8 vb = *(const bf16x8*)&Vt[vbase + (size_t)(n * 16 + lr) * S_ +
                                                kv0 + ksl * 32 + lg * 8];
#pragma unroll
                for (int qi = 0; qi < 2; ++qi) MFMA(acc[qi][n], pf[qi][ksl], vb);
            }
    }

    const int b = bh >> 4, h = bh & 15;
#pragma unroll
    for (int qi = 0; qi < 2; ++qi)
#pragma unroll
        for (int r4 = 0; r4 < 4; ++r4) {
            const int s = wq0 + qi * 16 + lg * 4 + r4;
            const float linv = 1.0f / l_[qi][r4];
#pragma unroll
            for (int n = 0; n < 4; ++n)
                CTX[(size_t)(b * S_ + s) * D_ + h * HD_ + n * 16 + lr] =
                    f2bf(acc[qi][n][r4] * linv);
        }
}

// ---------------------------------------------------------------------------
extern "C" void kernel_launch(void* const* d_in, const int* in_sizes, int n_in,
                              void* d_out, int out_size, void* d_ws, size_t ws_size,
                              hipStream_t stream)
{
    const float* x  = (const float*)d_in[0];
    const float* wq = (const float*)d_in[1];
    const float* bq = (const float*)d_in[2];
    const float* wk = (const float*)d_in[3];
    const float* bk = (const float*)d_in[4];
    const float* wv = (const float*)d_in[5];
    const float* bv = (const float*)d_in[6];
    const float* wo = (const float*)d_in[7];
    const float* bo = (const float*)d_in[8];

    char* ws = (char*)d_ws;
    u16*   xb    = (u16*)ws;                       // 8 MB (reused as ctx)
    u16*   WtAll = (u16*)(ws + (size_t)8  * 1024 * 1024);   // 8 MB, rows q|k|v|o
    u16*   qkv   = (u16*)(ws + (size_t)16 * 1024 * 1024);   // 24 MB: q | k | vT
    float* bias3 = (float*)(ws + (size_t)40 * 1024 * 1024); // 12 KB
    u16*   ctx   = xb;                              // alias: xb dead after QKV GEMM

    hipMemcpyAsync(bias3,        bq, D_ * 4, hipMemcpyDeviceToDevice, stream);
    hipMemcpyAsync(bias3 + D_,   bk, D_ * 4, hipMemcpyDeviceToDevice, stream);
    hipMemcpyAsync(bias3 + 2*D_, bv, D_ * 4, hipMemcpyDeviceToDevice, stream);

    cvt_x<<<2048, 256, 0, stream>>>(x, xb);
    cvt_w<<<dim3(16, 16, 4), 256, 0, stream>>>(wq, wk, wv, wo, WtAll);

    // fused QKV projection: N = 3072
    gemm2<128, 0><<<dim3(24, 32), 256, 0, stream>>>(xb, WtAll, bias3, qkv);

    // attention
    attn3<<<dim3(64, 32), 64, 0, stream>>>(qkv, qkv + NEL, qkv + 2 * (size_t)NEL, ctx);

    // output projection: N = 1024, f32 out
    gemm2<64, 1><<<dim3(8, 64), 256, 0, stream>>>(ctx, WtAll + (size_t)3072 * K_, bo,
                                                  d_out);
}

// Round 4
// 171.379 us; speedup vs baseline: 2.4108x; 1.4953x over previous
//
#include <hip/hip_runtime.h>

#define S_  2048
#define D_  1024
#define H_  16
#define HD_ 64
#define M_  4096
#define K_  1024
#define NEL 4194304   // B*H*S*HD

typedef short  bf16x8 __attribute__((ext_vector_type(8)));
typedef float  f32x4  __attribute__((ext_vector_type(4)));
typedef float  f32x16 __attribute__((ext_vector_type(16)));
typedef unsigned int   u32;
typedef unsigned int   u32x4v __attribute__((ext_vector_type(4)));
typedef unsigned short u16;
typedef unsigned short u16x4 __attribute__((ext_vector_type(4)));

#define MFMA16(c,a,b) (c) = __builtin_amdgcn_mfma_f32_16x16x32_bf16((a),(b),(c),0,0,0)
#define MFMA32(c,a,b) (c) = __builtin_amdgcn_mfma_f32_32x32x16_bf16((a),(b),(c),0,0,0)

// Q pre-scale: 1/sqrt(64) * log2(e) -> softmax in exp2 domain
#define QSCALE 0.18033688011112042f

__device__ __forceinline__ u16 f2bf(float f) {
    union { float f; unsigned u; } v; v.f = f;
    unsigned u = v.u;
    u += 0x7FFFu + ((u >> 16) & 1u);   // RNE
    return (u16)(u >> 16);
}

__device__ __forceinline__ u32 cvtpk(float lo, float hi) {
    u32 r;
    asm("v_cvt_pk_bf16_f32 %0, %1, %2" : "=v"(r) : "v"(lo), "v"(hi));
    return r;
}

__device__ __forceinline__ void gload16(const void* g, void* l) {
    __builtin_amdgcn_global_load_lds(
        (const __attribute__((address_space(1))) unsigned*)g,
        (__attribute__((address_space(3))) unsigned*)l, 16, 0, 0);
}

// ---------------------------------------------------------------------------
__global__ __launch_bounds__(256) void cvt_x(const float* __restrict__ x,
                                             u16* __restrict__ xb) {
    const int i = (blockIdx.x * 256 + threadIdx.x) * 8;
    f32x4 a = *(const f32x4*)&x[i];
    f32x4 b = *(const f32x4*)&x[i + 4];
    u16 t[8];
#pragma unroll
    for (int j = 0; j < 4; ++j) { t[j] = f2bf(a[j]); t[4 + j] = f2bf(b[j]); }
    *(bf16x8*)&xb[i] = *(const bf16x8*)t;
}

// ---------------------------------------------------------------------------
__global__ __launch_bounds__(256) void cvt_w(const float* __restrict__ w0,
                                             const float* __restrict__ w1,
                                             const float* __restrict__ w2,
                                             const float* __restrict__ w3,
                                             u16* __restrict__ Wt) {
    __shared__ float T[64][65];
    const float* W = blockIdx.z == 0 ? w0 : blockIdx.z == 1 ? w1
                   : blockIdx.z == 2 ? w2 : w3;
    const int k0 = blockIdx.x * 64, n0 = blockIdx.y * 64;
    const int r  = threadIdx.x >> 2, c0 = (threadIdx.x & 3) * 16;
#pragma unroll
    for (int j = 0; j < 4; ++j)
        *(f32x4*)&T[r][c0 + j * 4] = *(const f32x4*)&W[(size_t)(k0 + r) * D_ + n0 + c0 + j * 4];
    __syncthreads();
    u16 tmp[16];
#pragma unroll
    for (int j = 0; j < 16; ++j) tmp[j] = f2bf(T[c0 + j][r]);
    u16* dst = Wt + ((size_t)blockIdx.z * 1024 + n0 + r) * K_ + k0 + c0;
    *(bf16x8*)dst       = *(const bf16x8*)tmp;
    *(bf16x8*)(dst + 8) = *(const bf16x8*)(tmp + 8);
}

// ---------------------------------------------------------------------------
// m97-style GEMM (unchanged from round 3).
// ---------------------------------------------------------------------------
template <int BM, int MODE>
__global__ __launch_bounds__(256) void gemm2(
    const u16* __restrict__ A, const u16* __restrict__ Bt,
    const float* __restrict__ bias, void* __restrict__ Out)
{
    __shared__ u16 As[BM * 32];
    __shared__ u16 Bs[128 * 32];
    const int tid = threadIdx.x, lane = tid & 63, wid = tid >> 6;
    const int lr = lane & 15, lg = lane >> 4;
    const int n0 = blockIdx.x * 128, m0 = blockIdx.y * BM;
    const int wm = (wid >> 1) * (BM / 2), wn = (wid & 1) * 64;
    const int lrow = lane >> 2, lch = lane & 3;

    f32x4 acc[BM / 32][4] = {};

    for (int k0 = 0; k0 < K_; k0 += 32) {
        __syncthreads();
#pragma unroll
        for (int t = 0; t < BM / 64; ++t) {
            const int row = wid * (BM / 4) + t * 16 + lrow;
            gload16(A + (size_t)(m0 + row) * K_ + k0 + lch * 8,
                    (u16*)As + row * 32 + lch * 8);
        }
#pragma unroll
        for (int t = 0; t < 2; ++t) {
            const int row = wid * 32 + t * 16 + lrow;
            gload16(Bt + (size_t)(n0 + row) * K_ + k0 + lch * 8,
                    (u16*)Bs + row * 32 + lch * 8);
        }
        __syncthreads();

        bf16x8 af[BM / 32], bf[4];
#pragma unroll
        for (int i = 0; i < BM / 32; ++i)
            af[i] = *(const bf16x8*)&As[(wm + i * 16 + lr) * 32 + lg * 8];
#pragma unroll
        for (int j = 0; j < 4; ++j)
            bf[j] = *(const bf16x8*)&Bs[(wn + j * 16 + lr) * 32 + lg * 8];
#pragma unroll
        for (int i = 0; i < BM / 32; ++i)
#pragma unroll
            for (int j = 0; j < 4; ++j) MFMA16(acc[i][j], af[i], bf[j]);
    }

#pragma unroll
    for (int i = 0; i < BM / 32; ++i) {
#pragma unroll
        for (int j = 0; j < 4; ++j) {
            const int n = n0 + wn + j * 16 + lr;
            const float bv = bias[n];
            const int m = m0 + wm + i * 16 + lg * 4;
            if constexpr (MODE == 0) {
                u16* qkv = (u16*)Out;
                const int which = n >> 10, nn = n & 1023;
                const int h = nn >> 6, hd = nn & 63;
                const int b = m >> 11, s = m & 2047;
                if (which == 2) {                         // V: [bh][hd][s]
                    u16x4 pk;
#pragma unroll
                    for (int r4 = 0; r4 < 4; ++r4) pk[r4] = f2bf(acc[i][j][r4] + bv);
                    *(u16x4*)&qkv[(size_t)2 * NEL +
                                  ((size_t)(b * H_ + h) * HD_ + hd) * S_ + s] = pk;
                } else {                                  // Q/K: [bh][s][hd]
                    const float sc = (which == 0) ? QSCALE : 1.0f;
                    const size_t bas = (size_t)which * NEL + (size_t)(b * H_ + h) * S_ * HD_;
#pragma unroll
                    for (int r4 = 0; r4 < 4; ++r4)
                        qkv[bas + (size_t)(s + r4) * HD_ + hd] =
                            f2bf((acc[i][j][r4] + bv) * sc);
                }
            } else {
                float* o = (float*)Out;
#pragma unroll
                for (int r4 = 0; r4 < 4; ++r4)
                    o[(size_t)(m + r4) * D_ + n] = acc[i][j][r4] + bv;
            }
        }
    }
}

// ---------------------------------------------------------------------------
// attn4: swapped-QK^T flash attention, causal, exp2 domain.  1 wave / block,
// 32 q-rows / wave, KV tiles 64, mfma 32x32x16.  Zero LDS, zero barriers.
// S^T = K·Q^T: lane holds P-row for q=lane&31 (32 of 64 kv; partner lane^32
// has the rest).  Softmax lane-local; P->A-frag in registers via cvt_pk +
// shfl_xor(32).  C/D: col=lane&31, row=(r&3)+8(r>>2)+4*(lane>>5) [m74/m101].
// ---------------------------------------------------------------------------
__global__ __launch_bounds__(64) void attn4(
    const u16* __restrict__ Q, const u16* __restrict__ K,
    const u16* __restrict__ Vt, u16* __restrict__ CTX)
{
    const int lane = threadIdx.x & 63;
    const int lo = lane & 31, hi = lane >> 5;
    const int idx = blockIdx.x;
    const int bh  = idx & 31;              // consecutive blocks = consecutive bh
    const int qb  = 63 - (idx >> 5);       // heavy q-blocks dispatched first
    const int wq0 = qb * 32;
    const size_t base  = (size_t)bh * S_ * HD_;   // Q,K: [bh][s][hd]
    const size_t vbase = (size_t)bh * HD_ * S_;   // Vt:  [bh][hd][s]

    // Q as B-fragment: lane holds col q=lo, k = 16*ks + 8*hi + j
    bf16x8 qf[4];
#pragma unroll
    for (int ks = 0; ks < 4; ++ks)
        qf[ks] = *(const bf16x8*)&Q[base + (size_t)(wq0 + lo) * HD_ + ks * 16 + hi * 8];

    f32x16 acc[2] = {};                     // O accumulator, d-tiles 0/1
    float m_ = -1e30f, l_ = 0.f;
    const int nt = (wq0 >> 6) + 1;

    for (int t = 0; t < nt; ++t) {
        const int kv0 = t * 64;
        const bool sub1 = (kv0 + 32 <= wq0 + 31);  // 2nd kv-subtile has live cols

        // ---- QK^T (S^T): A = K rows, B = Q ----
        f32x16 cT[2];
#pragma unroll
        for (int i = 0; i < 16; ++i) { cT[0][i] = 0.f; cT[1][i] = 0.f; }
#pragma unroll
        for (int ks = 0; ks < 4; ++ks) {
            bf16x8 kf = *(const bf16x8*)&K[base + (size_t)(kv0 + lo) * HD_ + ks * 16 + hi * 8];
            MFMA32(cT[0], kf, qf[ks]);
        }
        if (sub1) {
#pragma unroll
            for (int ks = 0; ks < 4; ++ks) {
                bf16x8 kf = *(const bf16x8*)&K[base + (size_t)(kv0 + 32 + lo) * HD_ + ks * 16 + hi * 8];
                MFMA32(cT[1], kf, qf[ks]);
            }
        }

        // ---- V B-frags issued early (hide under softmax) ----
        bf16x8 vf[2][4];
#pragma unroll
        for (int dt = 0; dt < 2; ++dt)
#pragma unroll
            for (int ks = 0; ks < 4; ++ks)
                if (ks < 2 || sub1)
                    vf[dt][ks] = *(const bf16x8*)&Vt[vbase + (size_t)(dt * 32 + lo) * S_ +
                                                     kv0 + ks * 16 + hi * 8];

        // ---- causal mask (diagonal passes only) ----
        if (kv0 + 63 > wq0) {
            const int qg = wq0 + lo;
#pragma unroll
            for (int tt = 0; tt < 2; ++tt)
#pragma unroll
                for (int r = 0; r < 16; ++r) {
                    const int kvg = kv0 + tt * 32 + (r & 3) + 8 * (r >> 2) + 4 * hi;
                    if (kvg > qg) cT[tt][r] = -1e9f;
                }
        }

        // ---- row max: in-register tree + 1 cross-lane ----
        float m8[8];
#pragma unroll
        for (int i = 0; i < 8; ++i)
            m8[i] = fmaxf(fmaxf(cT[0][i], cT[0][i + 8]), fmaxf(cT[1][i], cT[1][i + 8]));
        float mx = fmaxf(fmaxf(fmaxf(m8[0], m8[1]), fmaxf(m8[2], m8[3])),
                         fmaxf(fmaxf(m8[4], m8[5]), fmaxf(m8[6], m8[7])));
        mx = fmaxf(mx, __shfl_xor(mx, 32));

        // ---- defer-max (T13, exp2 domain: 11.5 = 8*log2e) ----
        if (!__all(mx <= m_ + 11.5f)) {
            const float mn = fmaxf(m_, mx);
            const float al = exp2f(m_ - mn);
            m_ = mn; l_ *= al;
            float alr[16];
#pragma unroll
            for (int r = 0; r < 16; ++r)
                alr[r] = __shfl(al, (r & 3) + 8 * (r >> 2) + 4 * hi);
#pragma unroll
            for (int r = 0; r < 16; ++r) { acc[0][r] *= alr[r]; acc[1][r] *= alr[r]; }
        }

        // ---- P = exp2(S - m), lane-local sum + 1 cross-lane ----
#pragma unroll
        for (int i = 0; i < 16; ++i) {
            cT[0][i] = exp2f(cT[0][i] - m_);
            cT[1][i] = exp2f(cT[1][i] - m_);
        }
        float s8[8];
#pragma unroll
        for (int i = 0; i < 8; ++i)
            s8[i] = (cT[0][i] + cT[0][i + 8]) + (cT[1][i] + cT[1][i + 8]);
        float ssum = ((s8[0] + s8[1]) + (s8[2] + s8[3])) +
                     ((s8[4] + s8[5]) + (s8[6] + s8[7]));
        ssum += __shfl_xor(ssum, 32);
        l_ += ssum;

        // ---- pack P to bf16 pairs: pk[tt][w] = {kv'=.., kv'+1} ----
        u32 pk[2][8];
#pragma unroll
        for (int tt = 0; tt < 2; ++tt)
#pragma unroll
            for (int w = 0; w < 8; ++w)
                pk[tt][w] = cvtpk(cT[tt][2 * w], cT[tt][2 * w + 1]);

        // ---- build PV A-frags in registers; PV ----
#pragma unroll
        for (int ks = 0; ks < 4; ++ks) {
            if (ks < 2 || sub1) {
                const int tt = ks >> 1;
                const int ma = (2 * ks) & 3;       // m when hi=0
                const int mb = (2 * ks + 1) & 3;   // m when hi=1
                const u32 own0 = hi ? pk[tt][2 * mb]     : pk[tt][2 * ma];
                const u32 own1 = hi ? pk[tt][2 * mb + 1] : pk[tt][2 * ma + 1];
                const u32 snd0 = hi ? pk[tt][2 * ma]     : pk[tt][2 * mb];
                const u32 snd1 = hi ? pk[tt][2 * ma + 1] : pk[tt][2 * mb + 1];
                const u32 rcv0 = (u32)__shfl_xor((int)snd0, 32);
                const u32 rcv1 = (u32)__shfl_xor((int)snd1, 32);
                u32x4v afv;
                afv.x = hi ? rcv0 : own0;
                afv.y = hi ? rcv1 : own1;
                afv.z = hi ? own0 : rcv0;
                afv.w = hi ? own1 : rcv1;
                const bf16x8 af = __builtin_bit_cast(bf16x8, afv);
                MFMA32(acc[0], af, vf[0][ks]);
                MFMA32(acc[1], af, vf[1][ks]);
            }
        }
    }

    // ---- epilogue: normalize (redistribute 1/l to reg-q layout), store ----
    const float linv = 1.0f / l_;
    float lr[16];
#pragma unroll
    for (int r = 0; r < 16; ++r)
        lr[r] = __shfl(linv, (r & 3) + 8 * (r >> 2) + 4 * hi);
    const int b = bh >> 4, h = bh & 15;
#pragma unroll
    for (int r = 0; r < 16; ++r) {
        const int q = wq0 + (r & 3) + 8 * (r >> 2) + 4 * hi;
        u16* o = &CTX[(size_t)(b * S_ + q) * D_ + h * HD_ + lo];
        o[0]  = f2bf(acc[0][r] * lr[r]);
        o[32] = f2bf(acc[1][r] * lr[r]);
    }
}

// ---------------------------------------------------------------------------
extern "C" void kernel_launch(void* const* d_in, const int* in_sizes, int n_in,
                              void* d_out, int out_size, void* d_ws, size_t ws_size,
                              hipStream_t stream)
{
    const float* x  = (const float*)d_in[0];
    const float* wq = (const float*)d_in[1];
    const float* bq = (const float*)d_in[2];
    const float* wk = (const float*)d_in[3];
    const float* bk = (const float*)d_in[4];
    const float* wv = (const float*)d_in[5];
    const float* bv = (const float*)d_in[6];
    const float* wo = (const float*)d_in[7];
    const float* bo = (const float*)d_in[8];

    char* ws = (char*)d_ws;
    u16*   xb    = (u16*)ws;                                  // 8 MB (reused as ctx)
    u16*   WtAll = (u16*)(ws + (size_t)8  * 1024 * 1024);     // 8 MB, rows q|k|v|o
    u16*   qkv   = (u16*)(ws + (size_t)16 * 1024 * 1024);     // 24 MB: q | k | vT
    float* bias3 = (float*)(ws + (size_t)40 * 1024 * 1024);   // 12 KB
    u16*   ctx   = xb;

    hipMemcpyAsync(bias3,          bq, D_ * 4, hipMemcpyDeviceToDevice, stream);
    hipMemcpyAsync(bias3 + D_,     bk, D_ * 4, hipMemcpyDeviceToDevice, stream);
    hipMemcpyAsync(bias3 + 2 * D_, bv, D_ * 4, hipMemcpyDeviceToDevice, stream);

    cvt_x<<<2048, 256, 0, stream>>>(x, xb);
    cvt_w<<<dim3(16, 16, 4), 256, 0, stream>>>(wq, wk, wv, wo, WtAll);

    gemm2<128, 0><<<dim3(24, 32), 256, 0, stream>>>(xb, WtAll, bias3, qkv);

    attn4<<<dim3(2048), 64, 0, stream>>>(qkv, qkv + NEL, qkv + 2 * (size_t)NEL, ctx);

    gemm2<64, 1><<<dim3(8, 64), 256, 0, stream>>>(ctx, WtAll + (size_t)3072 * K_, bo,
                                                  d_out);
}

// Round 5
// 158.077 us; speedup vs baseline: 2.6137x; 1.0841x over previous
//
#include <hip/hip_runtime.h>

#define S_  2048
#define D_  1024
#define H_  16
#define HD_ 64
#define M_  4096
#define K_  1024
#define NEL 4194304   // B*H*S*HD

typedef short  bf16x8 __attribute__((ext_vector_type(8)));
typedef float  f32x4  __attribute__((ext_vector_type(4)));
typedef float  f32x16 __attribute__((ext_vector_type(16)));
typedef unsigned int   u32;
typedef unsigned int   u32x4v __attribute__((ext_vector_type(4)));
typedef unsigned short u16;
typedef unsigned short u16x4 __attribute__((ext_vector_type(4)));

#define MFMA16(c,a,b) (c) = __builtin_amdgcn_mfma_f32_16x16x32_bf16((a),(b),(c),0,0,0)
#define MFMA32(c,a,b) (c) = __builtin_amdgcn_mfma_f32_32x32x16_bf16((a),(b),(c),0,0,0)

// Q pre-scale: 1/sqrt(64) * log2(e) -> softmax in exp2 domain
#define QSCALE 0.18033688011112042f

__device__ __forceinline__ u16 f2bf(float f) {
    union { float f; unsigned u; } v; v.f = f;
    unsigned u = v.u;
    u += 0x7FFFu + ((u >> 16) & 1u);   // RNE
    return (u16)(u >> 16);
}

__device__ __forceinline__ u32 cvtpk(float lo, float hi) {
    u32 r;
    asm("v_cvt_pk_bf16_f32 %0, %1, %2" : "=v"(r) : "v"(lo), "v"(hi));
    return r;
}

__device__ __forceinline__ void gload16(const void* g, void* l) {
    __builtin_amdgcn_global_load_lds(
        (const __attribute__((address_space(1))) unsigned*)g,
        (__attribute__((address_space(3))) unsigned*)l, 16, 0, 0);
}

// ---------------------------------------------------------------------------
__global__ __launch_bounds__(256) void cvt_x(const float* __restrict__ x,
                                             u16* __restrict__ xb) {
    const int i = (blockIdx.x * 256 + threadIdx.x) * 8;
    f32x4 a = *(const f32x4*)&x[i];
    f32x4 b = *(const f32x4*)&x[i + 4];
    u16 t[8];
#pragma unroll
    for (int j = 0; j < 4; ++j) { t[j] = f2bf(a[j]); t[4 + j] = f2bf(b[j]); }
    *(bf16x8*)&xb[i] = *(const bf16x8*)t;
}

// ---------------------------------------------------------------------------
__global__ __launch_bounds__(256) void cvt_w(const float* __restrict__ w0,
                                             const float* __restrict__ w1,
                                             const float* __restrict__ w2,
                                             const float* __restrict__ w3,
                                             u16* __restrict__ Wt) {
    __shared__ float T[64][65];
    const float* W = blockIdx.z == 0 ? w0 : blockIdx.z == 1 ? w1
                   : blockIdx.z == 2 ? w2 : w3;
    const int k0 = blockIdx.x * 64, n0 = blockIdx.y * 64;
    const int r  = threadIdx.x >> 2, c0 = (threadIdx.x & 3) * 16;
#pragma unroll
    for (int j = 0; j < 4; ++j)
        *(f32x4*)&T[r][c0 + j * 4] = *(const f32x4*)&W[(size_t)(k0 + r) * D_ + n0 + c0 + j * 4];
    __syncthreads();
    u16 tmp[16];
#pragma unroll
    for (int j = 0; j < 16; ++j) tmp[j] = f2bf(T[c0 + j][r]);
    u16* dst = Wt + ((size_t)blockIdx.z * 1024 + n0 + r) * K_ + k0 + c0;
    *(bf16x8*)dst       = *(const bf16x8*)tmp;
    *(bf16x8*)(dst + 8) = *(const bf16x8*)(tmp + 8);
}

// ---------------------------------------------------------------------------
// m97-style GEMM (unchanged).
// ---------------------------------------------------------------------------
template <int BM, int MODE>
__global__ __launch_bounds__(256) void gemm2(
    const u16* __restrict__ A, const u16* __restrict__ Bt,
    const float* __restrict__ bias, void* __restrict__ Out)
{
    __shared__ u16 As[BM * 32];
    __shared__ u16 Bs[128 * 32];
    const int tid = threadIdx.x, lane = tid & 63, wid = tid >> 6;
    const int lr = lane & 15, lg = lane >> 4;
    const int n0 = blockIdx.x * 128, m0 = blockIdx.y * BM;
    const int wm = (wid >> 1) * (BM / 2), wn = (wid & 1) * 64;
    const int lrow = lane >> 2, lch = lane & 3;

    f32x4 acc[BM / 32][4] = {};

    for (int k0 = 0; k0 < K_; k0 += 32) {
        __syncthreads();
#pragma unroll
        for (int t = 0; t < BM / 64; ++t) {
            const int row = wid * (BM / 4) + t * 16 + lrow;
            gload16(A + (size_t)(m0 + row) * K_ + k0 + lch * 8,
                    (u16*)As + row * 32 + lch * 8);
        }
#pragma unroll
        for (int t = 0; t < 2; ++t) {
            const int row = wid * 32 + t * 16 + lrow;
            gload16(Bt + (size_t)(n0 + row) * K_ + k0 + lch * 8,
                    (u16*)Bs + row * 32 + lch * 8);
        }
        __syncthreads();

        bf16x8 af[BM / 32], bf[4];
#pragma unroll
        for (int i = 0; i < BM / 32; ++i)
            af[i] = *(const bf16x8*)&As[(wm + i * 16 + lr) * 32 + lg * 8];
#pragma unroll
        for (int j = 0; j < 4; ++j)
            bf[j] = *(const bf16x8*)&Bs[(wn + j * 16 + lr) * 32 + lg * 8];
#pragma unroll
        for (int i = 0; i < BM / 32; ++i)
#pragma unroll
            for (int j = 0; j < 4; ++j) MFMA16(acc[i][j], af[i], bf[j]);
    }

#pragma unroll
    for (int i = 0; i < BM / 32; ++i) {
#pragma unroll
        for (int j = 0; j < 4; ++j) {
            const int n = n0 + wn + j * 16 + lr;
            const float bv = bias[n];
            const int m = m0 + wm + i * 16 + lg * 4;
            if constexpr (MODE == 0) {
                u16* qkv = (u16*)Out;
                const int which = n >> 10, nn = n & 1023;
                const int h = nn >> 6, hd = nn & 63;
                const int b = m >> 11, s = m & 2047;
                if (which == 2) {                         // V: [bh][hd][s]
                    u16x4 pk;
#pragma unroll
                    for (int r4 = 0; r4 < 4; ++r4) pk[r4] = f2bf(acc[i][j][r4] + bv);
                    *(u16x4*)&qkv[(size_t)2 * NEL +
                                  ((size_t)(b * H_ + h) * HD_ + hd) * S_ + s] = pk;
                } else {                                  // Q/K: [bh][s][hd]
                    const float sc = (which == 0) ? QSCALE : 1.0f;
                    const size_t bas = (size_t)which * NEL + (size_t)(b * H_ + h) * S_ * HD_;
#pragma unroll
                    for (int r4 = 0; r4 < 4; ++r4)
                        qkv[bas + (size_t)(s + r4) * HD_ + hd] =
                            f2bf((acc[i][j][r4] + bv) * sc);
                }
            } else {
                float* o = (float*)Out;
#pragma unroll
                for (int r4 = 0; r4 < 4; ++r4)
                    o[(size_t)(m + r4) * D_ + n] = acc[i][j][r4] + bv;
            }
        }
    }
}

// ---------------------------------------------------------------------------
// attn5: attn4's swapped-QK^T datapath + KV-split x2.  Block = 2 waves, one
// (bh, 32-row q-block); wave w handles kv tiles t = w, w+2, ...; in-block
// merge via LDS (m = max, a_i = exp2(m_i - m), O = sum a_i O_i, l = sum a_i l_i).
// C/D layout: col=lane&31, row=(r&3)+8(r>>2)+4*(lane>>5)  [m74/m101].
// ---------------------------------------------------------------------------
__global__ __launch_bounds__(128) void attn5(
    const u16* __restrict__ Q, const u16* __restrict__ K,
    const u16* __restrict__ Vt, u16* __restrict__ CTX)
{
    __shared__ float OB[64][33];   // wave1 partial O (r-space), pad -> conflict-free
    __shared__ float MB[64], LB[64];

    const int tid  = threadIdx.x;
    const int lane = tid & 63, wv = tid >> 6;
    const int lo = lane & 31, hi = lane >> 5;
    const int idx = blockIdx.x;
    const int bh  = idx & 31;
    const int qb  = 63 - (idx >> 5);       // heavy q-blocks first
    const int wq0 = qb * 32;
    const size_t base  = (size_t)bh * S_ * HD_;   // Q,K: [bh][s][hd]
    const size_t vbase = (size_t)bh * HD_ * S_;   // Vt:  [bh][hd][s]

    // Q as B-fragment: lane holds col q=lo, k = 16*ks + 8*hi + j
    bf16x8 qf[4];
#pragma unroll
    for (int ks = 0; ks < 4; ++ks)
        qf[ks] = *(const bf16x8*)&Q[base + (size_t)(wq0 + lo) * HD_ + ks * 16 + hi * 8];

    f32x16 acc[2] = {};
    float m_ = -1e30f, l_ = 0.f;
    const int nt = (wq0 >> 6) + 1;

    for (int t = wv; t < nt; t += 2) {
        const int kv0 = t * 64;
        const bool sub1 = (kv0 + 32 <= wq0 + 31);

        // ---- QK^T (S^T): A = K rows, B = Q ----
        f32x16 cT[2];
#pragma unroll
        for (int i = 0; i < 16; ++i) { cT[0][i] = 0.f; cT[1][i] = 0.f; }
        __builtin_amdgcn_s_setprio(1);
#pragma unroll
        for (int ks = 0; ks < 4; ++ks) {
            bf16x8 kf = *(const bf16x8*)&K[base + (size_t)(kv0 + lo) * HD_ + ks * 16 + hi * 8];
            MFMA32(cT[0], kf, qf[ks]);
        }
        if (sub1) {
#pragma unroll
            for (int ks = 0; ks < 4; ++ks) {
                bf16x8 kf = *(const bf16x8*)&K[base + (size_t)(kv0 + 32 + lo) * HD_ + ks * 16 + hi * 8];
                MFMA32(cT[1], kf, qf[ks]);
            }
        }
        __builtin_amdgcn_s_setprio(0);

        // ---- V B-frags issued early (hide under softmax) ----
        bf16x8 vf[2][4];
#pragma unroll
        for (int dt = 0; dt < 2; ++dt)
#pragma unroll
            for (int ks = 0; ks < 4; ++ks)
                if (ks < 2 || sub1)
                    vf[dt][ks] = *(const bf16x8*)&Vt[vbase + (size_t)(dt * 32 + lo) * S_ +
                                                     kv0 + ks * 16 + hi * 8];

        // ---- causal mask (diagonal passes only) ----
        if (kv0 + 63 > wq0) {
            const int qg = wq0 + lo;
#pragma unroll
            for (int tt = 0; tt < 2; ++tt)
#pragma unroll
                for (int r = 0; r < 16; ++r) {
                    const int kvg = kv0 + tt * 32 + (r & 3) + 8 * (r >> 2) + 4 * hi;
                    if (kvg > qg) cT[tt][r] = -1e9f;
                }
        }

        // ---- row max: in-register tree + 1 cross-lane ----
        float m8[8];
#pragma unroll
        for (int i = 0; i < 8; ++i)
            m8[i] = fmaxf(fmaxf(cT[0][i], cT[0][i + 8]), fmaxf(cT[1][i], cT[1][i + 8]));
        float mx = fmaxf(fmaxf(fmaxf(m8[0], m8[1]), fmaxf(m8[2], m8[3])),
                         fmaxf(fmaxf(m8[4], m8[5]), fmaxf(m8[6], m8[7])));
        mx = fmaxf(mx, __shfl_xor(mx, 32));

        // ---- defer-max (T13, exp2 domain: 11.5 = 8*log2e) ----
        if (!__all(mx <= m_ + 11.5f)) {
            const float mn = fmaxf(m_, mx);
            const float al = exp2f(m_ - mn);
            m_ = mn; l_ *= al;
            float alr[16];
#pragma unroll
            for (int r = 0; r < 16; ++r)
                alr[r] = __shfl(al, (r & 3) + 8 * (r >> 2) + 4 * hi);
#pragma unroll
            for (int r = 0; r < 16; ++r) { acc[0][r] *= alr[r]; acc[1][r] *= alr[r]; }
        }

        // ---- P = exp2(S - m), lane-local sum + 1 cross-lane ----
#pragma unroll
        for (int i = 0; i < 16; ++i) {
            cT[0][i] = exp2f(cT[0][i] - m_);
            cT[1][i] = exp2f(cT[1][i] - m_);
        }
        float s8[8];
#pragma unroll
        for (int i = 0; i < 8; ++i)
            s8[i] = (cT[0][i] + cT[0][i + 8]) + (cT[1][i] + cT[1][i + 8]);
        float ssum = ((s8[0] + s8[1]) + (s8[2] + s8[3])) +
                     ((s8[4] + s8[5]) + (s8[6] + s8[7]));
        ssum += __shfl_xor(ssum, 32);
        l_ += ssum;

        // ---- pack P to bf16 pairs ----
        u32 pk[2][8];
#pragma unroll
        for (int tt = 0; tt < 2; ++tt)
#pragma unroll
            for (int w = 0; w < 8; ++w)
                pk[tt][w] = cvtpk(cT[tt][2 * w], cT[tt][2 * w + 1]);

        // ---- build PV A-frags in registers; PV ----
#pragma unroll
        for (int ks = 0; ks < 4; ++ks) {
            if (ks < 2 || sub1) {
                const int tt = ks >> 1;
                const int ma = (2 * ks) & 3;
                const int mb = (2 * ks + 1) & 3;
                const u32 own0 = hi ? pk[tt][2 * mb]     : pk[tt][2 * ma];
                const u32 own1 = hi ? pk[tt][2 * mb + 1] : pk[tt][2 * ma + 1];
                const u32 snd0 = hi ? pk[tt][2 * ma]     : pk[tt][2 * mb];
                const u32 snd1 = hi ? pk[tt][2 * ma + 1] : pk[tt][2 * mb + 1];
                const u32 rcv0 = (u32)__shfl_xor((int)snd0, 32);
                const u32 rcv1 = (u32)__shfl_xor((int)snd1, 32);
                u32x4v afv;
                afv.x = hi ? rcv0 : own0;
                afv.y = hi ? rcv1 : own1;
                afv.z = hi ? own0 : rcv0;
                afv.w = hi ? own1 : rcv1;
                const bf16x8 af = __builtin_bit_cast(bf16x8, afv);
                __builtin_amdgcn_s_setprio(1);
                MFMA32(acc[0], af, vf[0][ks]);
                MFMA32(acc[1], af, vf[1][ks]);
                __builtin_amdgcn_s_setprio(0);
            }
        }
    }

    // ---- in-block merge: wave1 publishes, wave0 combines + stores ----
    if (wv == 1) {
#pragma unroll
        for (int r = 0; r < 16; ++r) {
            OB[lane][r]      = acc[0][r];
            OB[lane][16 + r] = acc[1][r];
        }
        MB[lane] = m_;
        LB[lane] = l_;
    }
    __syncthreads();
    if (wv != 0) return;

    const float m1 = MB[lane], l1 = LB[lane];
    const float mM = fmaxf(m_, m1);
    const float a0 = exp2f(m_ - mM), a1 = exp2f(m1 - mM);
    l_ = l_ * a0 + l1 * a1;
    float a0r[16], a1r[16];
#pragma unroll
    for (int r = 0; r < 16; ++r) {
        const int rq = (r & 3) + 8 * (r >> 2) + 4 * hi;
        a0r[r] = __shfl(a0, rq);
        a1r[r] = __shfl(a1, rq);
    }
#pragma unroll
    for (int r = 0; r < 16; ++r) {
        acc[0][r] = acc[0][r] * a0r[r] + OB[lane][r]      * a1r[r];
        acc[1][r] = acc[1][r] * a0r[r] + OB[lane][16 + r] * a1r[r];
    }

    const float linv = 1.0f / l_;
    float lrr[16];
#pragma unroll
    for (int r = 0; r < 16; ++r)
        lrr[r] = __shfl(linv, (r & 3) + 8 * (r >> 2) + 4 * hi);
    const int b = bh >> 4, h = bh & 15;
#pragma unroll
    for (int r = 0; r < 16; ++r) {
        const int q = wq0 + (r & 3) + 8 * (r >> 2) + 4 * hi;
        u16* o = &CTX[(size_t)(b * S_ + q) * D_ + h * HD_ + lo];
        o[0]  = f2bf(acc[0][r] * lrr[r]);
        o[32] = f2bf(acc[1][r] * lrr[r]);
    }
}

// ---------------------------------------------------------------------------
extern "C" void kernel_launch(void* const* d_in, const int* in_sizes, int n_in,
                              void* d_out, int out_size, void* d_ws, size_t ws_size,
                              hipStream_t stream)
{
    const float* x  = (const float*)d_in[0];
    const float* wq = (const float*)d_in[1];
    const float* bq = (const float*)d_in[2];
    const float* wk = (const float*)d_in[3];
    const float* bk = (const float*)d_in[4];
    const float* wv = (const float*)d_in[5];
    const float* bv = (const float*)d_in[6];
    const float* wo = (const float*)d_in[7];
    const float* bo = (const float*)d_in[8];

    char* ws = (char*)d_ws;
    u16*   xb    = (u16*)ws;                                  // 8 MB (reused as ctx)
    u16*   WtAll = (u16*)(ws + (size_t)8  * 1024 * 1024);     // 8 MB, rows q|k|v|o
    u16*   qkv   = (u16*)(ws + (size_t)16 * 1024 * 1024);     // 24 MB: q | k | vT
    float* bias3 = (float*)(ws + (size_t)40 * 1024 * 1024);   // 12 KB
    u16*   ctx   = xb;

    hipMemcpyAsync(bias3,          bq, D_ * 4, hipMemcpyDeviceToDevice, stream);
    hipMemcpyAsync(bias3 + D_,     bk, D_ * 4, hipMemcpyDeviceToDevice, stream);
    hipMemcpyAsync(bias3 + 2 * D_, bv, D_ * 4, hipMemcpyDeviceToDevice, stream);

    cvt_x<<<2048, 256, 0, stream>>>(x, xb);
    cvt_w<<<dim3(16, 16, 4), 256, 0, stream>>>(wq, wk, wv, wo, WtAll);

    gemm2<128, 0><<<dim3(24, 32), 256, 0, stream>>>(xb, WtAll, bias3, qkv);

    attn5<<<dim3(2048), 128, 0, stream>>>(qkv, qkv + NEL, qkv + 2 * (size_t)NEL, ctx);

    gemm2<64, 1><<<dim3(8, 64), 256, 0, stream>>>(ctx, WtAll + (size_t)3072 * K_, bo,
                                                  d_out);
}